// Round 16
// baseline (59.624 us; speedup 1.0000x reference)
//
#include <hip/hip_runtime.h>
#include <hip/hip_bf16.h>

// EquivariantConvolution via bf16 MFMA — R16: load-balance experiment. BM 256->128,
// TPB 512->256, grid 1024->2048 (8 blocks/CU dispatched, ~6 resident + refill) to
// smooth straggler CUs (R12-R15 post-mortem: occupancy pinned at ~46% with zero
// refill at grid==4 blocks/CU; all other levers neutral). Pieces: R15-certified
// wave-local prologue (BM const only), R4/R10-proven 256-thread write_stage
// verbatim, R12-proven K-loop/bias/epilogue with q in {0,1}, wid 0..3.
// LDS = hT 8K + region 16K = 24KB. __launch_bounds__(256,3) = R10 no-spill config.
// GEMM view: C[e,a] = sum_{j,b} (h[e,j]*tmp[e,b]) * w2[j, a*32+b], K=1056 incl bias, N=32.

#define TPB 256
#define BM  128

typedef __attribute__((ext_vector_type(8))) short bf16x8;
typedef __attribute__((ext_vector_type(4))) float f32x4;
typedef __attribute__((ext_vector_type(4))) unsigned int u32x4;

__device__ __forceinline__ ushort f2bf(float x) {
    __hip_bfloat16 b = __float2bfloat16(x);
    return __builtin_bit_cast(ushort, b);
}
__device__ __forceinline__ float bf2f(ushort u) {
    unsigned int v = ((unsigned int)u) << 16;
    return __builtin_bit_cast(float, v);
}
// pack trunc-bf16(m0), trunc-bf16(m1) into one u32 (m0 -> low16, m1 -> high16)
__device__ __forceinline__ unsigned int pack_trunc(float m0, float m1) {
    return __builtin_amdgcn_perm(__builtin_bit_cast(unsigned int, m1),
                                 __builtin_bit_cast(unsigned int, m0),
                                 0x07060302u);
}

__global__ __launch_bounds__(TPB, 3) void equiv_conv_mfma(
    const float* __restrict__ basis1,
    const float* __restrict__ basis2,
    const float* __restrict__ ef,
    const float* __restrict__ f,
    const int*   __restrict__ src_idx,
    const float* __restrict__ w1,
    const float* __restrict__ b1,
    const float* __restrict__ w2,
    const float* __restrict__ b2,
    float* __restrict__ out)
{
    // LDS: hT 8KB + shared region 16KB (tmpT first 8KB, then WL 16KB) = 24KB.
    __shared__ ushort hT[32 * BM];        // [j][edge]  bf16 bits
    __shared__ ushort region[8192];       // tmpT [g][edge][8] (8KB), then WL [jr][g][a][i] (16KB)

    ushort* tmpT = region;
    ushort* WL   = region;

    const int tid  = threadIdx.x;
    const int base = blockIdx.x * BM;

    const int jr = tid >> 5;      // row-in-chunk this thread stages (0..7)
    const int tt = tid & 31;

    // ---- issue chunk-0 w2 loads early (land under prologue compute) ----
    // (R4/R10-proven 256-thread staging, verbatim)
    f32x4 stg[8];
    {
        const float* p = w2 + jr * 1024 + tt * 4;
        #pragma unroll
        for (int i = 0; i < 8; ++i)
            stg[i] = *reinterpret_cast<const f32x4*>(p + i * 128);
    }

    auto write_stage = [&]() {
        const int g   = (tt >> 1) & 3;
        const int i0v = (tt & 1) * 4;
        #pragma unroll
        for (int i = 0; i < 8; ++i) {
            const int a = i * 4 + (tt >> 3);
            unsigned int lo = (unsigned int)f2bf(stg[i][0]) | ((unsigned int)f2bf(stg[i][1]) << 16);
            unsigned int hi = (unsigned int)f2bf(stg[i][2]) | ((unsigned int)f2bf(stg[i][3]) << 16);
            *reinterpret_cast<uint2*>(&WL[jr * 1024 + g * 256 + a * 8 + i0v]) =
                make_uint2(lo, hi);
        }
    };

    // ---- wave-local prologue (R15-certified): 4 waves, lane half-split ----
    const int lane = tid & 63;
    const int wid  = tid >> 6;             // 0..3, owns edges wid*32 .. wid*32+31
    const int el   = lane & 31;            // edge-in-wave
    const int half = lane >> 5;            // 0/1: j/m range split
    const int e    = base + wid * 32 + el;

    // h: lane computes j = half*16 .. half*16+15 for edge e
    {
        f32x4 ef4[4];
        const f32x4* p4 = reinterpret_cast<const f32x4*>(ef + e * 16);
        #pragma unroll
        for (int i = 0; i < 4; ++i) ef4[i] = p4[i];

        float hacc[16];
        {
            const f32x4* b14 = reinterpret_cast<const f32x4*>(b1 + half * 16);
            #pragma unroll
            for (int p = 0; p < 4; ++p) {
                f32x4 b = b14[p];
                hacc[p*4+0] = b[0]; hacc[p*4+1] = b[1];
                hacc[p*4+2] = b[2]; hacc[p*4+3] = b[3];
            }
        }
        #pragma unroll
        for (int i = 0; i < 16; ++i) {
            const float efi = ef4[i >> 2][i & 3];
            const f32x4* w14 = reinterpret_cast<const f32x4*>(w1 + i * 32 + half * 16);
            #pragma unroll
            for (int p = 0; p < 4; ++p) {
                f32x4 wv = w14[p];
                hacc[p*4+0] = fmaf(efi, wv[0], hacc[p*4+0]);
                hacc[p*4+1] = fmaf(efi, wv[1], hacc[p*4+1]);
                hacc[p*4+2] = fmaf(efi, wv[2], hacc[p*4+2]);
                hacc[p*4+3] = fmaf(efi, wv[3], hacc[p*4+3]);
            }
        }
        #pragma unroll
        for (int jj = 0; jj < 16; ++jj)
            hT[(half * 16 + jj) * BM + wid * 32 + el] = f2bf(fmaxf(hacc[jj], 0.f));
    }

    // tmp: lane computes rows m = half*4 .. half*4+3 for edge e
    {
        const int s = src_idx[e];
        f32x4 fr4[4];
        const f32x4* p4 = reinterpret_cast<const f32x4*>(f + s * 32 + half * 16);
        #pragma unroll
        for (int i = 0; i < 4; ++i) fr4[i] = p4[i];
        f32x4 b14[4];
        const f32x4* q4 = reinterpret_cast<const f32x4*>(basis1 + e * 16);
        #pragma unroll
        for (int i = 0; i < 4; ++i) b14[i] = q4[i];

        f32x4 acc4[4];
        #pragma unroll
        for (int ml = 0; ml < 4; ++ml) {
            acc4[ml] = fr4[ml][0] * b14[0];
            #pragma unroll
            for (int d = 1; d < 4; ++d)
                acc4[ml] += fr4[ml][d] * b14[d];
        }
        float tl[16];
        #pragma unroll
        for (int ml = 0; ml < 4; ++ml) {
            tl[ml*4+0] = acc4[ml][0]; tl[ml*4+1] = acc4[ml][1];
            tl[ml*4+2] = acc4[ml][2]; tl[ml*4+3] = acc4[ml][3];
        }
        #pragma unroll
        for (int gl = 0; gl < 2; ++gl) {   // global g = half*2 + gl
            uint4 pk;
            pk.x = (unsigned int)f2bf(tl[gl*8+0]) | ((unsigned int)f2bf(tl[gl*8+1]) << 16);
            pk.y = (unsigned int)f2bf(tl[gl*8+2]) | ((unsigned int)f2bf(tl[gl*8+3]) << 16);
            pk.z = (unsigned int)f2bf(tl[gl*8+4]) | ((unsigned int)f2bf(tl[gl*8+5]) << 16);
            pk.w = (unsigned int)f2bf(tl[gl*8+6]) | ((unsigned int)f2bf(tl[gl*8+7]) << 16);
            *reinterpret_cast<uint4*>(
                &tmpT[((half * 2 + gl) * BM + wid * 32 + el) * 8]) = pk;
        }
    }

    __syncthreads();                       // hT/tmpT visible

    // ---- per-wave tile setup: read tmpf BEFORE region is reused as WL ----
    const int l15  = lane & 15;
    const int lg   = lane >> 4;            // K-group (b = lg*8 + i)

    float tmpf[2][8];                      // per-tile tmp[b] as f32, K-loop invariant
    #pragma unroll
    for (int q = 0; q < 2; ++q) {
        const int edge = wid * 32 + q * 16 + l15;
        bf16x8 tv = *reinterpret_cast<const bf16x8*>(&tmpT[(lg * BM + edge) * 8]);
        #pragma unroll
        for (int i = 0; i < 8; ++i) tmpf[q][i] = bf2f((ushort)tv[i]);
    }

    __syncthreads();                       // WAR: all waves done reading tmpT region
    write_stage();                         // chunk 0 -> WL (same region)
    __syncthreads();                       // WL ready

    f32x4 acc[2][2];
    #pragma unroll
    for (int q = 0; q < 2; ++q) {
        #pragma unroll
        for (int t = 0; t < 2; ++t) {
            acc[q][t][0] = 0.f; acc[q][t][1] = 0.f; acc[q][t][2] = 0.f; acc[q][t][3] = 0.f;
        }
    }

    // ---- K-loop: 4 chunks x 8 rows, single-buffered WL ----
    #pragma unroll 1
    for (int c = 0; c < 4; ++c) {
        if (c < 3) {
            const float* p = w2 + ((c + 1) * 8 + jr) * 1024 + tt * 4;
            #pragma unroll
            for (int i = 0; i < 8; ++i)
                stg[i] = *reinterpret_cast<const f32x4*>(p + i * 128);
        } else if (tid < 32) {             // bias2 row (jr==0, tt==tid)
            const float* p = b2 + tt * 4;
            #pragma unroll
            for (int i = 0; i < 8; ++i)
                stg[i] = *reinterpret_cast<const f32x4*>(p + i * 128);
        }

        const ushort* Wb = WL;
        #pragma unroll
        for (int j8 = 0; j8 < 8; ++j8) {
            const int kk = c * 8 + j8;
            bf16x8 bf0 = *reinterpret_cast<const bf16x8*>(&Wb[j8 * 1024 + lg * 256 + l15 * 8]);
            bf16x8 bf1 = *reinterpret_cast<const bf16x8*>(&Wb[j8 * 1024 + lg * 256 + (16 + l15) * 8]);
            #pragma unroll
            for (int q = 0; q < 2; ++q) {
                const float hv = bf2f(hT[kk * BM + wid * 32 + q * 16 + l15]);
                u32x4 w;
                #pragma unroll
                for (int i = 0; i < 4; ++i)
                    w[i] = pack_trunc(hv * tmpf[q][2*i], hv * tmpf[q][2*i+1]);
                const bf16x8 af = __builtin_bit_cast(bf16x8, w);
                acc[q][0] = __builtin_amdgcn_mfma_f32_16x16x32_bf16(af, bf0, acc[q][0], 0, 0, 0);
                acc[q][1] = __builtin_amdgcn_mfma_f32_16x16x32_bf16(af, bf1, acc[q][1], 0, 0, 0);
            }
        }

        __syncthreads();                   // everyone done reading WL
        if (c < 3) write_stage();
        else if (tid < 32) write_stage();  // bias row into row 0
        __syncthreads();                   // WL ready for next chunk / bias step
    }

    // ---- bias2 K-step (implicit h == 1, A = trunc(tmpf) == original bf16 bits) ----
    {
        bf16x8 bb0 = *reinterpret_cast<const bf16x8*>(&WL[lg * 256 + l15 * 8]);
        bf16x8 bb1 = *reinterpret_cast<const bf16x8*>(&WL[lg * 256 + (16 + l15) * 8]);
        #pragma unroll
        for (int q = 0; q < 2; ++q) {
            u32x4 w;
            #pragma unroll
            for (int i = 0; i < 4; ++i)
                w[i] = pack_trunc(tmpf[q][2*i], tmpf[q][2*i+1]);   // exact (values are bf16)
            const bf16x8 af = __builtin_bit_cast(bf16x8, w);
            acc[q][0] = __builtin_amdgcn_mfma_f32_16x16x32_bf16(af, bb0, acc[q][0], 0, 0, 0);
            acc[q][1] = __builtin_amdgcn_mfma_f32_16x16x32_bf16(af, bb1, acc[q][1], 0, 0, 0);
        }
    }

    // ---- epilogue: out[e,m2,d2] = sum_k2 C[e, m2*4+k2] * basis2[e,k2,d2] ----
    // C layout (verified): col a = lane&15 (+16*t), row = (lane>>4)*4 + reg.
    const int k2  = lane & 3;
    const int m2l = (lane >> 2) & 3;
    #pragma unroll
    for (int q = 0; q < 2; ++q) {
        #pragma unroll
        for (int r = 0; r < 4; ++r) {
            const int eg = base + wid * 32 + q * 16 + lg * 4 + r;
            f32x4 bs2 = *reinterpret_cast<const f32x4*>(basis2 + eg * 16 + k2 * 4);
            #pragma unroll
            for (int t = 0; t < 2; ++t) {
                const float v = acc[q][t][r];
                float p0 = v * bs2[0], p1 = v * bs2[1], p2 = v * bs2[2], p3 = v * bs2[3];
                p0 += __shfl_xor(p0, 1); p0 += __shfl_xor(p0, 2);
                p1 += __shfl_xor(p1, 1); p1 += __shfl_xor(p1, 2);
                p2 += __shfl_xor(p2, 1); p2 += __shfl_xor(p2, 2);
                p3 += __shfl_xor(p3, 1); p3 += __shfl_xor(p3, 2);
                const float ov = (k2 == 0) ? p0 : (k2 == 1) ? p1 : (k2 == 2) ? p2 : p3;
                out[eg * 32 + (t * 4 + m2l) * 4 + k2] = ov;
            }
        }
    }
}

extern "C" void kernel_launch(void* const* d_in, const int* in_sizes, int n_in,
                              void* d_out, int out_size, void* d_ws, size_t ws_size,
                              hipStream_t stream) {
    const float* basis1 = (const float*)d_in[0];
    const float* basis2 = (const float*)d_in[1];
    const float* ef     = (const float*)d_in[2];
    const float* f      = (const float*)d_in[3];
    const int*   src    = (const int*)  d_in[4];
    const float* w1     = (const float*)d_in[5];
    const float* b1     = (const float*)d_in[6];
    const float* w2     = (const float*)d_in[7];
    const float* b2     = (const float*)d_in[8];
    float* out = (float*)d_out;

    const int E = in_sizes[4];            // 262144
    const int nblocks = E / BM;           // 2048

    equiv_conv_mfma<<<nblocks, TPB, 0, stream>>>(
        basis1, basis2, ef, f, src, w1, b1, w2, b2, out);
}

// Round 17
// 48.871 us; speedup vs baseline: 1.2200x; 1.2200x over previous
//
#include <hip/hip_runtime.h>
#include <hip/hip_bf16.h>

// EquivariantConvolution via bf16 MFMA — R17: exact R12 text (best, 48.0us) with ONE
// change: af-build products computed as float2 vector ops so the compiler can emit
// v_pk_mul_f32 (4 pk-mul + 4 perm = 8 VALU per (kk,q) vs 12). No layout/index change.
// R16 lesson: finer blocks double staging overhead (refill theory refuted).
// GEMM view: C[e,a] = sum_{j,b} (h[e,j]*tmp[e,b]) * w2[j, a*32+b], K=1056 incl bias, N=32.

#define TPB 512
#define BM  256

typedef __attribute__((ext_vector_type(8))) short bf16x8;
typedef __attribute__((ext_vector_type(2))) float f32x2;
typedef __attribute__((ext_vector_type(4))) float f32x4;
typedef __attribute__((ext_vector_type(4))) unsigned int u32x4;

__device__ __forceinline__ ushort f2bf(float x) {
    __hip_bfloat16 b = __float2bfloat16(x);
    return __builtin_bit_cast(ushort, b);
}
__device__ __forceinline__ float bf2f(ushort u) {
    unsigned int v = ((unsigned int)u) << 16;
    return __builtin_bit_cast(float, v);
}
// pack trunc-bf16(m0), trunc-bf16(m1) into one u32 (m0 -> low16, m1 -> high16)
__device__ __forceinline__ unsigned int pack_trunc(float m0, float m1) {
    return __builtin_amdgcn_perm(__builtin_bit_cast(unsigned int, m1),
                                 __builtin_bit_cast(unsigned int, m0),
                                 0x07060302u);
}

__global__ __launch_bounds__(TPB, 6) void equiv_conv_mfma(
    const float* __restrict__ basis1,
    const float* __restrict__ basis2,
    const float* __restrict__ ef,
    const float* __restrict__ f,
    const int*   __restrict__ src_idx,
    const float* __restrict__ w1,
    const float* __restrict__ b1,
    const float* __restrict__ w2,
    const float* __restrict__ b2,
    float* __restrict__ out)
{
    // LDS: hT 16KB + shared region 16KB (tmpT then WL) = 32 KB.
    __shared__ ushort hT[32 * BM];        // [j][edge]  bf16 bits
    __shared__ ushort region[8192];       // first tmpT [g][edge][8], then WL [jr][g][a][i]

    ushort* tmpT = region;
    ushort* WL   = region;

    const int tid  = threadIdx.x;
    const int base = blockIdx.x * BM;

    const int jr2 = tid >> 6;     // row-in-chunk this thread stages (0..7)
    const int tt2 = tid & 63;

    // ---- issue chunk-0 w2 loads early (land under prologue compute) ----
    f32x4 stg[4];
    {
        const float* p = w2 + jr2 * 1024 + tt2 * 4;
        #pragma unroll
        for (int i = 0; i < 4; ++i)
            stg[i] = *reinterpret_cast<const f32x4*>(p + i * 256);
    }

    // write staged regs (bf16) into WL; col = tt2*4 + i*256 + l:
    //   a = i*8 + (tt2>>3), b = (tt2&7)*4 + l -> g = (tt2>>1)&3, i0 = (tt2&1)*4.
    auto write_stage = [&]() {
        const int g   = (tt2 >> 1) & 3;
        const int i0v = (tt2 & 1) * 4;
        #pragma unroll
        for (int i = 0; i < 4; ++i) {
            const int a = i * 8 + (tt2 >> 3);
            unsigned int lo = (unsigned int)f2bf(stg[i][0]) | ((unsigned int)f2bf(stg[i][1]) << 16);
            unsigned int hi = (unsigned int)f2bf(stg[i][2]) | ((unsigned int)f2bf(stg[i][3]) << 16);
            *reinterpret_cast<uint2*>(&WL[jr2 * 1024 + g * 256 + a * 8 + i0v]) =
                make_uint2(lo, hi);
        }
    };

    // ---- prologue (edges are owned by threads 0..255) ----
    if (tid < BM) {
        const int e = base + tid;
        // h = relu(ef@w1 + b1) -> hT (bf16)
        {
            float efr[16];
            const f32x4* p4 = reinterpret_cast<const f32x4*>(ef + e * 16);
            #pragma unroll
            for (int i = 0; i < 4; ++i) {
                f32x4 v = p4[i];
                efr[i*4+0] = v[0]; efr[i*4+1] = v[1]; efr[i*4+2] = v[2]; efr[i*4+3] = v[3];
            }
            #pragma unroll
            for (int j = 0; j < 32; ++j) {
                float hv = b1[j];
                #pragma unroll
                for (int i = 0; i < 16; ++i)
                    hv = fmaf(efr[i], w1[i * 32 + j], hv);
                hT[j * BM + tid] = f2bf(fmaxf(hv, 0.f));
            }
        }
        // tmp[m*4+k] = sum_d f_src[m][d]*basis1[d][k] -> tmpT (bf16)
        {
            float fr[32];
            const int s = src_idx[e];
            const f32x4* p4 = reinterpret_cast<const f32x4*>(f + s * 32);
            #pragma unroll
            for (int i = 0; i < 8; ++i) {
                f32x4 v = p4[i];
                fr[i*4+0] = v[0]; fr[i*4+1] = v[1]; fr[i*4+2] = v[2]; fr[i*4+3] = v[3];
            }
            float bs1[16];
            const f32x4* q4 = reinterpret_cast<const f32x4*>(basis1 + e * 16);
            #pragma unroll
            for (int i = 0; i < 4; ++i) {
                f32x4 v = q4[i];
                bs1[i*4+0] = v[0]; bs1[i*4+1] = v[1]; bs1[i*4+2] = v[2]; bs1[i*4+3] = v[3];
            }
            float tmp[32];
            #pragma unroll
            for (int m = 0; m < 8; ++m) {
                #pragma unroll
                for (int k = 0; k < 4; ++k) {
                    float v = 0.f;
                    #pragma unroll
                    for (int d = 0; d < 4; ++d)
                        v = fmaf(fr[m*4+d], bs1[d*4+k], v);
                    tmp[m*4+k] = v;
                }
            }
            #pragma unroll
            for (int g = 0; g < 4; ++g) {
                uint4 pk;
                pk.x = (unsigned int)f2bf(tmp[g*8+0]) | ((unsigned int)f2bf(tmp[g*8+1]) << 16);
                pk.y = (unsigned int)f2bf(tmp[g*8+2]) | ((unsigned int)f2bf(tmp[g*8+3]) << 16);
                pk.z = (unsigned int)f2bf(tmp[g*8+4]) | ((unsigned int)f2bf(tmp[g*8+5]) << 16);
                pk.w = (unsigned int)f2bf(tmp[g*8+6]) | ((unsigned int)f2bf(tmp[g*8+7]) << 16);
                *reinterpret_cast<uint4*>(&tmpT[(g * BM + tid) * 8]) = pk;
            }
        }
    }

    __syncthreads();                       // tmpT/hT visible to all 8 waves

    // ---- per-wave tile setup: read tmpf BEFORE region is reused as WL ----
    const int lane = tid & 63;
    const int wid  = tid >> 6;             // 0..7, owns edges wid*32 .. wid*32+31
    const int l15  = lane & 15;
    const int lg   = lane >> 4;            // K-group (b = lg*8 + i)

    f32x2 tmp2[2][4];                      // per-tile tmp[b] as f32 pairs, K-loop invariant
    #pragma unroll
    for (int q = 0; q < 2; ++q) {
        const int edge = wid * 32 + q * 16 + l15;
        bf16x8 tv = *reinterpret_cast<const bf16x8*>(&tmpT[(lg * BM + edge) * 8]);
        #pragma unroll
        for (int i = 0; i < 4; ++i) {
            tmp2[q][i][0] = bf2f((ushort)tv[2*i]);
            tmp2[q][i][1] = bf2f((ushort)tv[2*i+1]);
        }
    }

    __syncthreads();                       // WAR: all waves done reading tmpT region
    write_stage();                         // chunk 0 -> WL (same region)
    __syncthreads();                       // WL ready

    f32x4 acc[2][2];
    #pragma unroll
    for (int q = 0; q < 2; ++q) {
        #pragma unroll
        for (int t = 0; t < 2; ++t) {
            acc[q][t][0] = 0.f; acc[q][t][1] = 0.f; acc[q][t][2] = 0.f; acc[q][t][3] = 0.f;
        }
    }

    // ---- K-loop: 4 chunks x 8 rows, single-buffered WL ----
    #pragma unroll 1
    for (int c = 0; c < 4; ++c) {
        // issue next chunk's global loads (write to LDS after compute + barrier)
        if (c < 3) {
            const float* p = w2 + ((c + 1) * 8 + jr2) * 1024 + tt2 * 4;
            #pragma unroll
            for (int i = 0; i < 4; ++i)
                stg[i] = *reinterpret_cast<const f32x4*>(p + i * 256);
        } else if (tid < 64) {             // bias2 row (jr2==0, tt2==tid)
            const float* p = b2 + tt2 * 4;
            #pragma unroll
            for (int i = 0; i < 4; ++i)
                stg[i] = *reinterpret_cast<const f32x4*>(p + i * 256);
        }

        const ushort* Wb = WL;
        #pragma unroll
        for (int j8 = 0; j8 < 8; ++j8) {
            const int kk = c * 8 + j8;
            bf16x8 bf0 = *reinterpret_cast<const bf16x8*>(&Wb[j8 * 1024 + lg * 256 + l15 * 8]);
            bf16x8 bf1 = *reinterpret_cast<const bf16x8*>(&Wb[j8 * 1024 + lg * 256 + (16 + l15) * 8]);
            #pragma unroll
            for (int q = 0; q < 2; ++q) {
                const float hv = bf2f(hT[kk * BM + wid * 32 + q * 16 + l15]);
                const f32x2 hv2 = (f32x2){hv, hv};
                u32x4 w;
                #pragma unroll
                for (int i = 0; i < 4; ++i) {
                    f32x2 m = hv2 * tmp2[q][i];            // v_pk_mul_f32
                    w[i] = pack_trunc(m[0], m[1]);
                }
                const bf16x8 af = __builtin_bit_cast(bf16x8, w);
                acc[q][0] = __builtin_amdgcn_mfma_f32_16x16x32_bf16(af, bf0, acc[q][0], 0, 0, 0);
                acc[q][1] = __builtin_amdgcn_mfma_f32_16x16x32_bf16(af, bf1, acc[q][1], 0, 0, 0);
            }
        }

        __syncthreads();                   // everyone done reading WL
        if (c < 3) write_stage();
        else if (tid < 64) write_stage();  // bias row into row 0
        __syncthreads();                   // WL ready for next chunk / bias step
    }

    // ---- bias2 K-step (implicit h == 1, A = trunc(tmp2) == original bf16 bits) ----
    {
        bf16x8 bb0 = *reinterpret_cast<const bf16x8*>(&WL[lg * 256 + l15 * 8]);
        bf16x8 bb1 = *reinterpret_cast<const bf16x8*>(&WL[lg * 256 + (16 + l15) * 8]);
        #pragma unroll
        for (int q = 0; q < 2; ++q) {
            u32x4 w;
            #pragma unroll
            for (int i = 0; i < 4; ++i)
                w[i] = pack_trunc(tmp2[q][i][0], tmp2[q][i][1]);   // exact (values are bf16)
            const bf16x8 af = __builtin_bit_cast(bf16x8, w);
            acc[q][0] = __builtin_amdgcn_mfma_f32_16x16x32_bf16(af, bb0, acc[q][0], 0, 0, 0);
            acc[q][1] = __builtin_amdgcn_mfma_f32_16x16x32_bf16(af, bb1, acc[q][1], 0, 0, 0);
        }
    }

    // ---- epilogue: out[e,m2,d2] = sum_k2 C[e, m2*4+k2] * basis2[e,k2,d2] ----
    // C layout (verified): col a = lane&15 (+16*t), row = (lane>>4)*4 + reg.
    const int k2  = lane & 3;
    const int m2l = (lane >> 2) & 3;
    #pragma unroll
    for (int q = 0; q < 2; ++q) {
        #pragma unroll
        for (int r = 0; r < 4; ++r) {
            const int eg = base + wid * 32 + q * 16 + lg * 4 + r;
            f32x4 bs2 = *reinterpret_cast<const f32x4*>(basis2 + eg * 16 + k2 * 4);
            #pragma unroll
            for (int t = 0; t < 2; ++t) {
                const float v = acc[q][t][r];
                float p0 = v * bs2[0], p1 = v * bs2[1], p2 = v * bs2[2], p3 = v * bs2[3];
                p0 += __shfl_xor(p0, 1); p0 += __shfl_xor(p0, 2);
                p1 += __shfl_xor(p1, 1); p1 += __shfl_xor(p1, 2);
                p2 += __shfl_xor(p2, 1); p2 += __shfl_xor(p2, 2);
                p3 += __shfl_xor(p3, 1); p3 += __shfl_xor(p3, 2);
                const float ov = (k2 == 0) ? p0 : (k2 == 1) ? p1 : (k2 == 2) ? p2 : p3;
                out[eg * 32 + (t * 4 + m2l) * 4 + k2] = ov;
            }
        }
    }
}

extern "C" void kernel_launch(void* const* d_in, const int* in_sizes, int n_in,
                              void* d_out, int out_size, void* d_ws, size_t ws_size,
                              hipStream_t stream) {
    const float* basis1 = (const float*)d_in[0];
    const float* basis2 = (const float*)d_in[1];
    const float* ef     = (const float*)d_in[2];
    const float* f      = (const float*)d_in[3];
    const int*   src    = (const int*)  d_in[4];
    const float* w1     = (const float*)d_in[5];
    const float* b1     = (const float*)d_in[6];
    const float* w2     = (const float*)d_in[7];
    const float* b2     = (const float*)d_in[8];
    float* out = (float*)d_out;

    const int E = in_sizes[4];            // 262144
    const int nblocks = E / BM;           // 1024

    equiv_conv_mfma<<<nblocks, TPB, 0, stream>>>(
        basis1, basis2, ef, f, src, w1, b1, w2, b2, out);
}

// Round 19
// 48.776 us; speedup vs baseline: 1.2224x; 1.0020x over previous
//
#include <hip/hip_runtime.h>
#include <hip/hip_bf16.h>

// EquivariantConvolution via bf16 MFMA — R19: R17 text (passed, 48.9us ~ R12's 48.0)
// with ONE change: per-chunk preload of the 16 h-values (8 kk x 2 q) into registers
// with static indexing, hoisting 64 serial in-loop ds_read_u16 latency exposures to
// 4 pipelined bursts. Same addresses/values; K-loop inner body is reg/VALU/MFMA + WL.
// R18 lesson: A/B MFMA operand lane-mappings are NOT swap-symmetric on gfx950
// (operand-swap C^T failed on HW) — epilogue stays in the verified butterfly form.
// GEMM view: C[e,a] = sum_{j,b} (h[e,j]*tmp[e,b]) * w2[j, a*32+b], K=1056 incl bias, N=32.

#define TPB 512
#define BM  256

typedef __attribute__((ext_vector_type(8))) short bf16x8;
typedef __attribute__((ext_vector_type(2))) float f32x2;
typedef __attribute__((ext_vector_type(4))) float f32x4;
typedef __attribute__((ext_vector_type(4))) unsigned int u32x4;

__device__ __forceinline__ ushort f2bf(float x) {
    __hip_bfloat16 b = __float2bfloat16(x);
    return __builtin_bit_cast(ushort, b);
}
__device__ __forceinline__ float bf2f(ushort u) {
    unsigned int v = ((unsigned int)u) << 16;
    return __builtin_bit_cast(float, v);
}
// pack trunc-bf16(m0), trunc-bf16(m1) into one u32 (m0 -> low16, m1 -> high16)
__device__ __forceinline__ unsigned int pack_trunc(float m0, float m1) {
    return __builtin_amdgcn_perm(__builtin_bit_cast(unsigned int, m1),
                                 __builtin_bit_cast(unsigned int, m0),
                                 0x07060302u);
}

__global__ __launch_bounds__(TPB, 6) void equiv_conv_mfma(
    const float* __restrict__ basis1,
    const float* __restrict__ basis2,
    const float* __restrict__ ef,
    const float* __restrict__ f,
    const int*   __restrict__ src_idx,
    const float* __restrict__ w1,
    const float* __restrict__ b1,
    const float* __restrict__ w2,
    const float* __restrict__ b2,
    float* __restrict__ out)
{
    // LDS: hT 16KB + shared region 16KB (tmpT then WL) = 32 KB.
    __shared__ ushort hT[32 * BM];        // [j][edge]  bf16 bits
    __shared__ ushort region[8192];       // first tmpT [g][edge][8], then WL [jr][g][a][i]

    ushort* tmpT = region;
    ushort* WL   = region;

    const int tid  = threadIdx.x;
    const int base = blockIdx.x * BM;

    const int jr2 = tid >> 6;     // row-in-chunk this thread stages (0..7)
    const int tt2 = tid & 63;

    // ---- issue chunk-0 w2 loads early (land under prologue compute) ----
    f32x4 stg[4];
    {
        const float* p = w2 + jr2 * 1024 + tt2 * 4;
        #pragma unroll
        for (int i = 0; i < 4; ++i)
            stg[i] = *reinterpret_cast<const f32x4*>(p + i * 256);
    }

    // write staged regs (bf16) into WL; col = tt2*4 + i*256 + l:
    //   a = i*8 + (tt2>>3), b = (tt2&7)*4 + l -> g = (tt2>>1)&3, i0 = (tt2&1)*4.
    auto write_stage = [&]() {
        const int g   = (tt2 >> 1) & 3;
        const int i0v = (tt2 & 1) * 4;
        #pragma unroll
        for (int i = 0; i < 4; ++i) {
            const int a = i * 8 + (tt2 >> 3);
            unsigned int lo = (unsigned int)f2bf(stg[i][0]) | ((unsigned int)f2bf(stg[i][1]) << 16);
            unsigned int hi = (unsigned int)f2bf(stg[i][2]) | ((unsigned int)f2bf(stg[i][3]) << 16);
            *reinterpret_cast<uint2*>(&WL[jr2 * 1024 + g * 256 + a * 8 + i0v]) =
                make_uint2(lo, hi);
        }
    };

    // ---- prologue (edges are owned by threads 0..255) ----
    if (tid < BM) {
        const int e = base + tid;
        // h = relu(ef@w1 + b1) -> hT (bf16)
        {
            float efr[16];
            const f32x4* p4 = reinterpret_cast<const f32x4*>(ef + e * 16);
            #pragma unroll
            for (int i = 0; i < 4; ++i) {
                f32x4 v = p4[i];
                efr[i*4+0] = v[0]; efr[i*4+1] = v[1]; efr[i*4+2] = v[2]; efr[i*4+3] = v[3];
            }
            #pragma unroll
            for (int j = 0; j < 32; ++j) {
                float hv = b1[j];
                #pragma unroll
                for (int i = 0; i < 16; ++i)
                    hv = fmaf(efr[i], w1[i * 32 + j], hv);
                hT[j * BM + tid] = f2bf(fmaxf(hv, 0.f));
            }
        }
        // tmp[m*4+k] = sum_d f_src[m][d]*basis1[d][k] -> tmpT (bf16)
        {
            float fr[32];
            const int s = src_idx[e];
            const f32x4* p4 = reinterpret_cast<const f32x4*>(f + s * 32);
            #pragma unroll
            for (int i = 0; i < 8; ++i) {
                f32x4 v = p4[i];
                fr[i*4+0] = v[0]; fr[i*4+1] = v[1]; fr[i*4+2] = v[2]; fr[i*4+3] = v[3];
            }
            float bs1[16];
            const f32x4* q4 = reinterpret_cast<const f32x4*>(basis1 + e * 16);
            #pragma unroll
            for (int i = 0; i < 4; ++i) {
                f32x4 v = q4[i];
                bs1[i*4+0] = v[0]; bs1[i*4+1] = v[1]; bs1[i*4+2] = v[2]; bs1[i*4+3] = v[3];
            }
            float tmp[32];
            #pragma unroll
            for (int m = 0; m < 8; ++m) {
                #pragma unroll
                for (int k = 0; k < 4; ++k) {
                    float v = 0.f;
                    #pragma unroll
                    for (int d = 0; d < 4; ++d)
                        v = fmaf(fr[m*4+d], bs1[d*4+k], v);
                    tmp[m*4+k] = v;
                }
            }
            #pragma unroll
            for (int g = 0; g < 4; ++g) {
                uint4 pk;
                pk.x = (unsigned int)f2bf(tmp[g*8+0]) | ((unsigned int)f2bf(tmp[g*8+1]) << 16);
                pk.y = (unsigned int)f2bf(tmp[g*8+2]) | ((unsigned int)f2bf(tmp[g*8+3]) << 16);
                pk.z = (unsigned int)f2bf(tmp[g*8+4]) | ((unsigned int)f2bf(tmp[g*8+5]) << 16);
                pk.w = (unsigned int)f2bf(tmp[g*8+6]) | ((unsigned int)f2bf(tmp[g*8+7]) << 16);
                *reinterpret_cast<uint4*>(&tmpT[(g * BM + tid) * 8]) = pk;
            }
        }
    }

    __syncthreads();                       // tmpT/hT visible to all 8 waves

    // ---- per-wave tile setup: read tmpf BEFORE region is reused as WL ----
    const int lane = tid & 63;
    const int wid  = tid >> 6;             // 0..7, owns edges wid*32 .. wid*32+31
    const int l15  = lane & 15;
    const int lg   = lane >> 4;            // K-group (b = lg*8 + i)

    f32x2 tmp2[2][4];                      // per-tile tmp[b] as f32 pairs, K-loop invariant
    #pragma unroll
    for (int q = 0; q < 2; ++q) {
        const int edge = wid * 32 + q * 16 + l15;
        bf16x8 tv = *reinterpret_cast<const bf16x8*>(&tmpT[(lg * BM + edge) * 8]);
        #pragma unroll
        for (int i = 0; i < 4; ++i) {
            tmp2[q][i][0] = bf2f((ushort)tv[2*i]);
            tmp2[q][i][1] = bf2f((ushort)tv[2*i+1]);
        }
    }

    __syncthreads();                       // WAR: all waves done reading tmpT region
    write_stage();                         // chunk 0 -> WL (same region)
    __syncthreads();                       // WL ready

    f32x4 acc[2][2];
    #pragma unroll
    for (int q = 0; q < 2; ++q) {
        #pragma unroll
        for (int t = 0; t < 2; ++t) {
            acc[q][t][0] = 0.f; acc[q][t][1] = 0.f; acc[q][t][2] = 0.f; acc[q][t][3] = 0.f;
        }
    }

    const ushort* hrow = &hT[wid * 32 + l15];   // + q*16 + kk*BM

    // ---- K-loop: 4 chunks x 8 rows, single-buffered WL ----
    #pragma unroll 1
    for (int c = 0; c < 4; ++c) {
        // issue next chunk's global loads (write to LDS after compute + barrier)
        if (c < 3) {
            const float* p = w2 + ((c + 1) * 8 + jr2) * 1024 + tt2 * 4;
            #pragma unroll
            for (int i = 0; i < 4; ++i)
                stg[i] = *reinterpret_cast<const f32x4*>(p + i * 256);
        } else if (tid < 64) {             // bias2 row (jr2==0, tt2==tid)
            const float* p = b2 + tt2 * 4;
            #pragma unroll
            for (int i = 0; i < 4; ++i)
                stg[i] = *reinterpret_cast<const f32x4*>(p + i * 256);
        }

        // ---- preload this chunk's 16 h-values (static indexing -> registers) ----
        ushort hreg[8][2];
        #pragma unroll
        for (int j8 = 0; j8 < 8; ++j8) {
            #pragma unroll
            for (int q = 0; q < 2; ++q)
                hreg[j8][q] = hrow[(c * 8 + j8) * BM + q * 16];
        }

        const ushort* Wb = WL;
        #pragma unroll
        for (int j8 = 0; j8 < 8; ++j8) {
            bf16x8 bf0 = *reinterpret_cast<const bf16x8*>(&Wb[j8 * 1024 + lg * 256 + l15 * 8]);
            bf16x8 bf1 = *reinterpret_cast<const bf16x8*>(&Wb[j8 * 1024 + lg * 256 + (16 + l15) * 8]);
            #pragma unroll
            for (int q = 0; q < 2; ++q) {
                const float hv = bf2f(hreg[j8][q]);
                const f32x2 hv2 = (f32x2){hv, hv};
                u32x4 w;
                #pragma unroll
                for (int i = 0; i < 4; ++i) {
                    f32x2 m = hv2 * tmp2[q][i];            // v_pk_mul_f32
                    w[i] = pack_trunc(m[0], m[1]);
                }
                const bf16x8 af = __builtin_bit_cast(bf16x8, w);
                acc[q][0] = __builtin_amdgcn_mfma_f32_16x16x32_bf16(af, bf0, acc[q][0], 0, 0, 0);
                acc[q][1] = __builtin_amdgcn_mfma_f32_16x16x32_bf16(af, bf1, acc[q][1], 0, 0, 0);
            }
        }

        __syncthreads();                   // everyone done reading WL
        if (c < 3) write_stage();
        else if (tid < 64) write_stage();  // bias row into row 0
        __syncthreads();                   // WL ready for next chunk / bias step
    }

    // ---- bias2 K-step (implicit h == 1, A = trunc(tmp2) == original bf16 bits) ----
    {
        bf16x8 bb0 = *reinterpret_cast<const bf16x8*>(&WL[lg * 256 + l15 * 8]);
        bf16x8 bb1 = *reinterpret_cast<const bf16x8*>(&WL[lg * 256 + (16 + l15) * 8]);
        #pragma unroll
        for (int q = 0; q < 2; ++q) {
            u32x4 w;
            #pragma unroll
            for (int i = 0; i < 4; ++i)
                w[i] = pack_trunc(tmp2[q][i][0], tmp2[q][i][1]);   // exact (values are bf16)
            const bf16x8 af = __builtin_bit_cast(bf16x8, w);
            acc[q][0] = __builtin_amdgcn_mfma_f32_16x16x32_bf16(af, bb0, acc[q][0], 0, 0, 0);
            acc[q][1] = __builtin_amdgcn_mfma_f32_16x16x32_bf16(af, bb1, acc[q][1], 0, 0, 0);
        }
    }

    // ---- epilogue: out[e,m2,d2] = sum_k2 C[e, m2*4+k2] * basis2[e,k2,d2] ----
    // C layout (verified): col a = lane&15 (+16*t), row = (lane>>4)*4 + reg.
    const int k2  = lane & 3;
    const int m2l = (lane >> 2) & 3;
    #pragma unroll
    for (int q = 0; q < 2; ++q) {
        #pragma unroll
        for (int r = 0; r < 4; ++r) {
            const int eg = base + wid * 32 + q * 16 + lg * 4 + r;
            f32x4 bs2 = *reinterpret_cast<const f32x4*>(basis2 + eg * 16 + k2 * 4);
            #pragma unroll
            for (int t = 0; t < 2; ++t) {
                const float v = acc[q][t][r];
                float p0 = v * bs2[0], p1 = v * bs2[1], p2 = v * bs2[2], p3 = v * bs2[3];
                p0 += __shfl_xor(p0, 1); p0 += __shfl_xor(p0, 2);
                p1 += __shfl_xor(p1, 1); p1 += __shfl_xor(p1, 2);
                p2 += __shfl_xor(p2, 1); p2 += __shfl_xor(p2, 2);
                p3 += __shfl_xor(p3, 1); p3 += __shfl_xor(p3, 2);
                const float ov = (k2 == 0) ? p0 : (k2 == 1) ? p1 : (k2 == 2) ? p2 : p3;
                out[eg * 32 + (t * 4 + m2l) * 4 + k2] = ov;
            }
        }
    }
}

extern "C" void kernel_launch(void* const* d_in, const int* in_sizes, int n_in,
                              void* d_out, int out_size, void* d_ws, size_t ws_size,
                              hipStream_t stream) {
    const float* basis1 = (const float*)d_in[0];
    const float* basis2 = (const float*)d_in[1];
    const float* ef     = (const float*)d_in[2];
    const float* f      = (const float*)d_in[3];
    const int*   src    = (const int*)  d_in[4];
    const float* w1     = (const float*)d_in[5];
    const float* b1     = (const float*)d_in[6];
    const float* w2     = (const float*)d_in[7];
    const float* b2     = (const float*)d_in[8];
    float* out = (float*)d_out;

    const int E = in_sizes[4];            // 262144
    const int nblocks = E / BM;           // 1024

    equiv_conv_mfma<<<nblocks, TPB, 0, stream>>>(
        basis1, basis2, ef, f, src, w1, b1, w2, b2, out);
}

// Round 20
// 43.934 us; speedup vs baseline: 1.3571x; 1.1102x over previous
//
#include <hip/hip_runtime.h>
#include <hip/hip_bf16.h>

// EquivariantConvolution via bf16 MFMA — R20: R19 text (passed, 48.8us) with ONE
// change: epilogue's 128 ds_bpermute/wave butterfly replaced by an explicit 4x4
// quad transpose (4 shfl_xor per (q,t), pure lane-index semantics, symbolically
// verified M2[p][s]=M[s][p]) + lane-local basis2 contraction + float4 stores.
// Uses only HW-verified facts: quad lanes hold k2, regs hold the edge dim.
// R18 lesson: A/B operand-swap C^T is NOT valid on gfx950; this does not use it.
// GEMM view: C[e,a] = sum_{j,b} (h[e,j]*tmp[e,b]) * w2[j, a*32+b], K=1056 incl bias, N=32.

#define TPB 512
#define BM  256

typedef __attribute__((ext_vector_type(8))) short bf16x8;
typedef __attribute__((ext_vector_type(2))) float f32x2;
typedef __attribute__((ext_vector_type(4))) float f32x4;
typedef __attribute__((ext_vector_type(4))) unsigned int u32x4;

__device__ __forceinline__ ushort f2bf(float x) {
    __hip_bfloat16 b = __float2bfloat16(x);
    return __builtin_bit_cast(ushort, b);
}
__device__ __forceinline__ float bf2f(ushort u) {
    unsigned int v = ((unsigned int)u) << 16;
    return __builtin_bit_cast(float, v);
}
// pack trunc-bf16(m0), trunc-bf16(m1) into one u32 (m0 -> low16, m1 -> high16)
__device__ __forceinline__ unsigned int pack_trunc(float m0, float m1) {
    return __builtin_amdgcn_perm(__builtin_bit_cast(unsigned int, m1),
                                 __builtin_bit_cast(unsigned int, m0),
                                 0x07060302u);
}

__global__ __launch_bounds__(TPB, 6) void equiv_conv_mfma(
    const float* __restrict__ basis1,
    const float* __restrict__ basis2,
    const float* __restrict__ ef,
    const float* __restrict__ f,
    const int*   __restrict__ src_idx,
    const float* __restrict__ w1,
    const float* __restrict__ b1,
    const float* __restrict__ w2,
    const float* __restrict__ b2,
    float* __restrict__ out)
{
    // LDS: hT 16KB + shared region 16KB (tmpT then WL) = 32 KB.
    __shared__ ushort hT[32 * BM];        // [j][edge]  bf16 bits
    __shared__ ushort region[8192];       // first tmpT [g][edge][8], then WL [jr][g][a][i]

    ushort* tmpT = region;
    ushort* WL   = region;

    const int tid  = threadIdx.x;
    const int base = blockIdx.x * BM;

    const int jr2 = tid >> 6;     // row-in-chunk this thread stages (0..7)
    const int tt2 = tid & 63;

    // ---- issue chunk-0 w2 loads early (land under prologue compute) ----
    f32x4 stg[4];
    {
        const float* p = w2 + jr2 * 1024 + tt2 * 4;
        #pragma unroll
        for (int i = 0; i < 4; ++i)
            stg[i] = *reinterpret_cast<const f32x4*>(p + i * 256);
    }

    // write staged regs (bf16) into WL; col = tt2*4 + i*256 + l:
    //   a = i*8 + (tt2>>3), b = (tt2&7)*4 + l -> g = (tt2>>1)&3, i0 = (tt2&1)*4.
    auto write_stage = [&]() {
        const int g   = (tt2 >> 1) & 3;
        const int i0v = (tt2 & 1) * 4;
        #pragma unroll
        for (int i = 0; i < 4; ++i) {
            const int a = i * 8 + (tt2 >> 3);
            unsigned int lo = (unsigned int)f2bf(stg[i][0]) | ((unsigned int)f2bf(stg[i][1]) << 16);
            unsigned int hi = (unsigned int)f2bf(stg[i][2]) | ((unsigned int)f2bf(stg[i][3]) << 16);
            *reinterpret_cast<uint2*>(&WL[jr2 * 1024 + g * 256 + a * 8 + i0v]) =
                make_uint2(lo, hi);
        }
    };

    // ---- prologue (edges are owned by threads 0..255) ----
    if (tid < BM) {
        const int e = base + tid;
        // h = relu(ef@w1 + b1) -> hT (bf16)
        {
            float efr[16];
            const f32x4* p4 = reinterpret_cast<const f32x4*>(ef + e * 16);
            #pragma unroll
            for (int i = 0; i < 4; ++i) {
                f32x4 v = p4[i];
                efr[i*4+0] = v[0]; efr[i*4+1] = v[1]; efr[i*4+2] = v[2]; efr[i*4+3] = v[3];
            }
            #pragma unroll
            for (int j = 0; j < 32; ++j) {
                float hv = b1[j];
                #pragma unroll
                for (int i = 0; i < 16; ++i)
                    hv = fmaf(efr[i], w1[i * 32 + j], hv);
                hT[j * BM + tid] = f2bf(fmaxf(hv, 0.f));
            }
        }
        // tmp[m*4+k] = sum_d f_src[m][d]*basis1[d][k] -> tmpT (bf16)
        {
            float fr[32];
            const int s = src_idx[e];
            const f32x4* p4 = reinterpret_cast<const f32x4*>(f + s * 32);
            #pragma unroll
            for (int i = 0; i < 8; ++i) {
                f32x4 v = p4[i];
                fr[i*4+0] = v[0]; fr[i*4+1] = v[1]; fr[i*4+2] = v[2]; fr[i*4+3] = v[3];
            }
            float bs1[16];
            const f32x4* q4 = reinterpret_cast<const f32x4*>(basis1 + e * 16);
            #pragma unroll
            for (int i = 0; i < 4; ++i) {
                f32x4 v = q4[i];
                bs1[i*4+0] = v[0]; bs1[i*4+1] = v[1]; bs1[i*4+2] = v[2]; bs1[i*4+3] = v[3];
            }
            float tmp[32];
            #pragma unroll
            for (int m = 0; m < 8; ++m) {
                #pragma unroll
                for (int k = 0; k < 4; ++k) {
                    float v = 0.f;
                    #pragma unroll
                    for (int d = 0; d < 4; ++d)
                        v = fmaf(fr[m*4+d], bs1[d*4+k], v);
                    tmp[m*4+k] = v;
                }
            }
            #pragma unroll
            for (int g = 0; g < 4; ++g) {
                uint4 pk;
                pk.x = (unsigned int)f2bf(tmp[g*8+0]) | ((unsigned int)f2bf(tmp[g*8+1]) << 16);
                pk.y = (unsigned int)f2bf(tmp[g*8+2]) | ((unsigned int)f2bf(tmp[g*8+3]) << 16);
                pk.z = (unsigned int)f2bf(tmp[g*8+4]) | ((unsigned int)f2bf(tmp[g*8+5]) << 16);
                pk.w = (unsigned int)f2bf(tmp[g*8+6]) | ((unsigned int)f2bf(tmp[g*8+7]) << 16);
                *reinterpret_cast<uint4*>(&tmpT[(g * BM + tid) * 8]) = pk;
            }
        }
    }

    __syncthreads();                       // tmpT/hT visible to all 8 waves

    // ---- per-wave tile setup: read tmpf BEFORE region is reused as WL ----
    const int lane = tid & 63;
    const int wid  = tid >> 6;             // 0..7, owns edges wid*32 .. wid*32+31
    const int l15  = lane & 15;
    const int lg   = lane >> 4;            // K-group (b = lg*8 + i)

    f32x2 tmp2[2][4];                      // per-tile tmp[b] as f32 pairs, K-loop invariant
    #pragma unroll
    for (int q = 0; q < 2; ++q) {
        const int edge = wid * 32 + q * 16 + l15;
        bf16x8 tv = *reinterpret_cast<const bf16x8*>(&tmpT[(lg * BM + edge) * 8]);
        #pragma unroll
        for (int i = 0; i < 4; ++i) {
            tmp2[q][i][0] = bf2f((ushort)tv[2*i]);
            tmp2[q][i][1] = bf2f((ushort)tv[2*i+1]);
        }
    }

    __syncthreads();                       // WAR: all waves done reading tmpT region
    write_stage();                         // chunk 0 -> WL (same region)
    __syncthreads();                       // WL ready

    f32x4 acc[2][2];
    #pragma unroll
    for (int q = 0; q < 2; ++q) {
        #pragma unroll
        for (int t = 0; t < 2; ++t) {
            acc[q][t][0] = 0.f; acc[q][t][1] = 0.f; acc[q][t][2] = 0.f; acc[q][t][3] = 0.f;
        }
    }

    const ushort* hrow = &hT[wid * 32 + l15];   // + q*16 + kk*BM

    // ---- K-loop: 4 chunks x 8 rows, single-buffered WL ----
    #pragma unroll 1
    for (int c = 0; c < 4; ++c) {
        // issue next chunk's global loads (write to LDS after compute + barrier)
        if (c < 3) {
            const float* p = w2 + ((c + 1) * 8 + jr2) * 1024 + tt2 * 4;
            #pragma unroll
            for (int i = 0; i < 4; ++i)
                stg[i] = *reinterpret_cast<const f32x4*>(p + i * 256);
        } else if (tid < 64) {             // bias2 row (jr2==0, tt2==tid)
            const float* p = b2 + tt2 * 4;
            #pragma unroll
            for (int i = 0; i < 4; ++i)
                stg[i] = *reinterpret_cast<const f32x4*>(p + i * 256);
        }

        // ---- preload this chunk's 16 h-values (static indexing -> registers) ----
        ushort hreg[8][2];
        #pragma unroll
        for (int j8 = 0; j8 < 8; ++j8) {
            #pragma unroll
            for (int q = 0; q < 2; ++q)
                hreg[j8][q] = hrow[(c * 8 + j8) * BM + q * 16];
        }

        const ushort* Wb = WL;
        #pragma unroll
        for (int j8 = 0; j8 < 8; ++j8) {
            bf16x8 bf0 = *reinterpret_cast<const bf16x8*>(&Wb[j8 * 1024 + lg * 256 + l15 * 8]);
            bf16x8 bf1 = *reinterpret_cast<const bf16x8*>(&Wb[j8 * 1024 + lg * 256 + (16 + l15) * 8]);
            #pragma unroll
            for (int q = 0; q < 2; ++q) {
                const float hv = bf2f(hreg[j8][q]);
                const f32x2 hv2 = (f32x2){hv, hv};
                u32x4 w;
                #pragma unroll
                for (int i = 0; i < 4; ++i) {
                    f32x2 m = hv2 * tmp2[q][i];            // v_pk_mul_f32
                    w[i] = pack_trunc(m[0], m[1]);
                }
                const bf16x8 af = __builtin_bit_cast(bf16x8, w);
                acc[q][0] = __builtin_amdgcn_mfma_f32_16x16x32_bf16(af, bf0, acc[q][0], 0, 0, 0);
                acc[q][1] = __builtin_amdgcn_mfma_f32_16x16x32_bf16(af, bf1, acc[q][1], 0, 0, 0);
            }
        }

        __syncthreads();                   // everyone done reading WL
        if (c < 3) write_stage();
        else if (tid < 64) write_stage();  // bias row into row 0
        __syncthreads();                   // WL ready for next chunk / bias step
    }

    // ---- bias2 K-step (implicit h == 1, A = trunc(tmp2) == original bf16 bits) ----
    {
        bf16x8 bb0 = *reinterpret_cast<const bf16x8*>(&WL[lg * 256 + l15 * 8]);
        bf16x8 bb1 = *reinterpret_cast<const bf16x8*>(&WL[lg * 256 + (16 + l15) * 8]);
        #pragma unroll
        for (int q = 0; q < 2; ++q) {
            u32x4 w;
            #pragma unroll
            for (int i = 0; i < 4; ++i)
                w[i] = pack_trunc(tmp2[q][i][0], tmp2[q][i][1]);   // exact (values are bf16)
            const bf16x8 af = __builtin_bit_cast(bf16x8, w);
            acc[q][0] = __builtin_amdgcn_mfma_f32_16x16x32_bf16(af, bb0, acc[q][0], 0, 0, 0);
            acc[q][1] = __builtin_amdgcn_mfma_f32_16x16x32_bf16(af, bb1, acc[q][1], 0, 0, 0);
        }
    }

    // ---- epilogue: 4x4 quad transpose, then lane-local basis2 contraction ----
    // C layout (verified): lane holds col a = l15 + 16t (k2 = lane&3), rows
    // edge = q*16 + lg*4 + r in regs. Quad transpose (lane-pos p <-> reg idx):
    // after it, lane p holds all four k2 values of edge q*16 + lg*4 + p.
    const int m2l = (lane >> 2) & 3;
    const int p0  = lane & 1;
    const int p1  = (lane >> 1) & 1;
    #pragma unroll
    for (int q = 0; q < 2; ++q) {
        const int egp = base + wid * 32 + q * 16 + lg * 4 + (lane & 3);
        const f32x4* bp = reinterpret_cast<const f32x4*>(basis2 + egp * 16);
        f32x4 bsr0 = bp[0], bsr1 = bp[1], bsr2 = bp[2], bsr3 = bp[3];
        #pragma unroll
        for (int t = 0; t < 2; ++t) {
            float v0 = acc[q][t][0], v1 = acc[q][t][1];
            float v2 = acc[q][t][2], v3 = acc[q][t][3];
            // step 1 (xor 1): even.v1 <-> odd.v0, even.v3 <-> odd.v2
            float s0 = p0 ? v0 : v1;
            float r0 = __shfl_xor(s0, 1);
            if (p0) v0 = r0; else v1 = r0;
            float s1 = p0 ? v2 : v3;
            float r1 = __shfl_xor(s1, 1);
            if (p0) v2 = r1; else v3 = r1;
            // step 2 (xor 2): low.v2 <-> high.v0, low.v3 <-> high.v1
            float u0 = p1 ? v0 : v2;
            float w0 = __shfl_xor(u0, 2);
            if (p1) v0 = w0; else v2 = w0;
            float u1 = p1 ? v1 : v3;
            float w1 = __shfl_xor(u1, 2);
            if (p1) v1 = w1; else v3 = w1;
            // v[s] = C[edge egp][m2 = t*4+m2l, k2 = s] -> lane-local contraction
            f32x4 o = v0 * bsr0;
            o += v1 * bsr1;
            o += v2 * bsr2;
            o += v3 * bsr3;
            *reinterpret_cast<f32x4*>(out + egp * 32 + (t * 4 + m2l) * 4) = o;
        }
    }
}

extern "C" void kernel_launch(void* const* d_in, const int* in_sizes, int n_in,
                              void* d_out, int out_size, void* d_ws, size_t ws_size,
                              hipStream_t stream) {
    const float* basis1 = (const float*)d_in[0];
    const float* basis2 = (const float*)d_in[1];
    const float* ef     = (const float*)d_in[2];
    const float* f      = (const float*)d_in[3];
    const int*   src    = (const int*)  d_in[4];
    const float* w1     = (const float*)d_in[5];
    const float* b1     = (const float*)d_in[6];
    const float* w2     = (const float*)d_in[7];
    const float* b2     = (const float*)d_in[8];
    float* out = (float*)d_out;

    const int E = in_sizes[4];            // 262144
    const int nblocks = E / BM;           // 1024

    equiv_conv_mfma<<<nblocks, TPB, 0, stream>>>(
        basis1, basis2, ef, f, src, w1, b1, w2, b2, out);
}

// Round 22
// 43.434 us; speedup vs baseline: 1.3727x; 1.0115x over previous
//
#include <hip/hip_runtime.h>
#include <hip/hip_bf16.h>

// EquivariantConvolution via bf16 MFMA — R22: exact R20 text (passed, 43.9us) with
// ONE change (bisecting R21's bundled failure): write_stage converts W with
// pack_trunc (1 v_perm per pair, positions HW-certified by R10-R20's A-fragment
// use) instead of __float2bfloat16 RNE (~5 VALU/elem). Prologue stays R20-scalar.
// If this fails, the perm model is wrong at a deeper level -> revert to R20.
// GEMM view: C[e,a] = sum_{j,b} (h[e,j]*tmp[e,b]) * w2[j, a*32+b], K=1056 incl bias, N=32.

#define TPB 512
#define BM  256

typedef __attribute__((ext_vector_type(8))) short bf16x8;
typedef __attribute__((ext_vector_type(2))) float f32x2;
typedef __attribute__((ext_vector_type(4))) float f32x4;
typedef __attribute__((ext_vector_type(4))) unsigned int u32x4;

__device__ __forceinline__ ushort f2bf(float x) {
    __hip_bfloat16 b = __float2bfloat16(x);
    return __builtin_bit_cast(ushort, b);
}
__device__ __forceinline__ float bf2f(ushort u) {
    unsigned int v = ((unsigned int)u) << 16;
    return __builtin_bit_cast(float, v);
}
// pack trunc-bf16(m0), trunc-bf16(m1) into one u32 (m0 -> low16, m1 -> high16)
__device__ __forceinline__ unsigned int pack_trunc(float m0, float m1) {
    return __builtin_amdgcn_perm(__builtin_bit_cast(unsigned int, m1),
                                 __builtin_bit_cast(unsigned int, m0),
                                 0x07060302u);
}

__global__ __launch_bounds__(TPB, 6) void equiv_conv_mfma(
    const float* __restrict__ basis1,
    const float* __restrict__ basis2,
    const float* __restrict__ ef,
    const float* __restrict__ f,
    const int*   __restrict__ src_idx,
    const float* __restrict__ w1,
    const float* __restrict__ b1,
    const float* __restrict__ w2,
    const float* __restrict__ b2,
    float* __restrict__ out)
{
    // LDS: hT 16KB + shared region 16KB (tmpT then WL) = 32 KB.
    __shared__ ushort hT[32 * BM];        // [j][edge]  bf16 bits
    __shared__ ushort region[8192];       // first tmpT [g][edge][8], then WL [jr][g][a][i]

    ushort* tmpT = region;
    ushort* WL   = region;

    const int tid  = threadIdx.x;
    const int base = blockIdx.x * BM;

    const int jr2 = tid >> 6;     // row-in-chunk this thread stages (0..7)
    const int tt2 = tid & 63;

    // ---- issue chunk-0 w2 loads early (land under prologue compute) ----
    f32x4 stg[4];
    {
        const float* p = w2 + jr2 * 1024 + tt2 * 4;
        #pragma unroll
        for (int i = 0; i < 4; ++i)
            stg[i] = *reinterpret_cast<const f32x4*>(p + i * 256);
    }

    // write staged regs (bf16, trunc) into WL; col = tt2*4 + i*256 + l:
    //   a = i*8 + (tt2>>3), b = (tt2&7)*4 + l -> g = (tt2>>1)&3, i0 = (tt2&1)*4.
    auto write_stage = [&]() {
        const int g   = (tt2 >> 1) & 3;
        const int i0v = (tt2 & 1) * 4;
        #pragma unroll
        for (int i = 0; i < 4; ++i) {
            const int a = i * 8 + (tt2 >> 3);
            *reinterpret_cast<uint2*>(&WL[jr2 * 1024 + g * 256 + a * 8 + i0v]) =
                make_uint2(pack_trunc(stg[i][0], stg[i][1]),
                           pack_trunc(stg[i][2], stg[i][3]));
        }
    };

    // ---- prologue (edges are owned by threads 0..255) ----
    if (tid < BM) {
        const int e = base + tid;
        // h = relu(ef@w1 + b1) -> hT (bf16)
        {
            float efr[16];
            const f32x4* p4 = reinterpret_cast<const f32x4*>(ef + e * 16);
            #pragma unroll
            for (int i = 0; i < 4; ++i) {
                f32x4 v = p4[i];
                efr[i*4+0] = v[0]; efr[i*4+1] = v[1]; efr[i*4+2] = v[2]; efr[i*4+3] = v[3];
            }
            #pragma unroll
            for (int j = 0; j < 32; ++j) {
                float hv = b1[j];
                #pragma unroll
                for (int i = 0; i < 16; ++i)
                    hv = fmaf(efr[i], w1[i * 32 + j], hv);
                hT[j * BM + tid] = f2bf(fmaxf(hv, 0.f));
            }
        }
        // tmp[m*4+k] = sum_d f_src[m][d]*basis1[d][k] -> tmpT (bf16)
        {
            float fr[32];
            const int s = src_idx[e];
            const f32x4* p4 = reinterpret_cast<const f32x4*>(f + s * 32);
            #pragma unroll
            for (int i = 0; i < 8; ++i) {
                f32x4 v = p4[i];
                fr[i*4+0] = v[0]; fr[i*4+1] = v[1]; fr[i*4+2] = v[2]; fr[i*4+3] = v[3];
            }
            float bs1[16];
            const f32x4* q4 = reinterpret_cast<const f32x4*>(basis1 + e * 16);
            #pragma unroll
            for (int i = 0; i < 4; ++i) {
                f32x4 v = q4[i];
                bs1[i*4+0] = v[0]; bs1[i*4+1] = v[1]; bs1[i*4+2] = v[2]; bs1[i*4+3] = v[3];
            }
            float tmp[32];
            #pragma unroll
            for (int m = 0; m < 8; ++m) {
                #pragma unroll
                for (int k = 0; k < 4; ++k) {
                    float v = 0.f;
                    #pragma unroll
                    for (int d = 0; d < 4; ++d)
                        v = fmaf(fr[m*4+d], bs1[d*4+k], v);
                    tmp[m*4+k] = v;
                }
            }
            #pragma unroll
            for (int g = 0; g < 4; ++g) {
                uint4 pk;
                pk.x = (unsigned int)f2bf(tmp[g*8+0]) | ((unsigned int)f2bf(tmp[g*8+1]) << 16);
                pk.y = (unsigned int)f2bf(tmp[g*8+2]) | ((unsigned int)f2bf(tmp[g*8+3]) << 16);
                pk.z = (unsigned int)f2bf(tmp[g*8+4]) | ((unsigned int)f2bf(tmp[g*8+5]) << 16);
                pk.w = (unsigned int)f2bf(tmp[g*8+6]) | ((unsigned int)f2bf(tmp[g*8+7]) << 16);
                *reinterpret_cast<uint4*>(&tmpT[(g * BM + tid) * 8]) = pk;
            }
        }
    }

    __syncthreads();                       // tmpT/hT visible to all 8 waves

    // ---- per-wave tile setup: read tmpf BEFORE region is reused as WL ----
    const int lane = tid & 63;
    const int wid  = tid >> 6;             // 0..7, owns edges wid*32 .. wid*32+31
    const int l15  = lane & 15;
    const int lg   = lane >> 4;            // K-group (b = lg*8 + i)

    f32x2 tmp2[2][4];                      // per-tile tmp[b] as f32 pairs, K-loop invariant
    #pragma unroll
    for (int q = 0; q < 2; ++q) {
        const int edge = wid * 32 + q * 16 + l15;
        bf16x8 tv = *reinterpret_cast<const bf16x8*>(&tmpT[(lg * BM + edge) * 8]);
        #pragma unroll
        for (int i = 0; i < 4; ++i) {
            tmp2[q][i][0] = bf2f((ushort)tv[2*i]);
            tmp2[q][i][1] = bf2f((ushort)tv[2*i+1]);
        }
    }

    __syncthreads();                       // WAR: all waves done reading tmpT region
    write_stage();                         // chunk 0 -> WL (same region)
    __syncthreads();                       // WL ready

    f32x4 acc[2][2];
    #pragma unroll
    for (int q = 0; q < 2; ++q) {
        #pragma unroll
        for (int t = 0; t < 2; ++t) {
            acc[q][t][0] = 0.f; acc[q][t][1] = 0.f; acc[q][t][2] = 0.f; acc[q][t][3] = 0.f;
        }
    }

    const ushort* hrow = &hT[wid * 32 + l15];   // + q*16 + kk*BM

    // ---- K-loop: 4 chunks x 8 rows, single-buffered WL ----
    #pragma unroll 1
    for (int c = 0; c < 4; ++c) {
        // issue next chunk's global loads (write to LDS after compute + barrier)
        if (c < 3) {
            const float* p = w2 + ((c + 1) * 8 + jr2) * 1024 + tt2 * 4;
            #pragma unroll
            for (int i = 0; i < 4; ++i)
                stg[i] = *reinterpret_cast<const f32x4*>(p + i * 256);
        } else if (tid < 64) {             // bias2 row (jr2==0, tt2==tid)
            const float* p = b2 + tt2 * 4;
            #pragma unroll
            for (int i = 0; i < 4; ++i)
                stg[i] = *reinterpret_cast<const f32x4*>(p + i * 256);
        }

        // ---- preload this chunk's 16 h-values (static indexing -> registers) ----
        ushort hreg[8][2];
        #pragma unroll
        for (int j8 = 0; j8 < 8; ++j8) {
            #pragma unroll
            for (int q = 0; q < 2; ++q)
                hreg[j8][q] = hrow[(c * 8 + j8) * BM + q * 16];
        }

        const ushort* Wb = WL;
        #pragma unroll
        for (int j8 = 0; j8 < 8; ++j8) {
            bf16x8 bf0 = *reinterpret_cast<const bf16x8*>(&Wb[j8 * 1024 + lg * 256 + l15 * 8]);
            bf16x8 bf1 = *reinterpret_cast<const bf16x8*>(&Wb[j8 * 1024 + lg * 256 + (16 + l15) * 8]);
            #pragma unroll
            for (int q = 0; q < 2; ++q) {
                const float hv = bf2f(hreg[j8][q]);
                const f32x2 hv2 = (f32x2){hv, hv};
                u32x4 w;
                #pragma unroll
                for (int i = 0; i < 4; ++i) {
                    f32x2 m = hv2 * tmp2[q][i];            // v_pk_mul_f32
                    w[i] = pack_trunc(m[0], m[1]);
                }
                const bf16x8 af = __builtin_bit_cast(bf16x8, w);
                acc[q][0] = __builtin_amdgcn_mfma_f32_16x16x32_bf16(af, bf0, acc[q][0], 0, 0, 0);
                acc[q][1] = __builtin_amdgcn_mfma_f32_16x16x32_bf16(af, bf1, acc[q][1], 0, 0, 0);
            }
        }

        __syncthreads();                   // everyone done reading WL
        if (c < 3) write_stage();
        else if (tid < 64) write_stage();  // bias row into row 0
        __syncthreads();                   // WL ready for next chunk / bias step
    }

    // ---- bias2 K-step (implicit h == 1, A = trunc(tmp2) == original bf16 bits) ----
    {
        bf16x8 bb0 = *reinterpret_cast<const bf16x8*>(&WL[lg * 256 + l15 * 8]);
        bf16x8 bb1 = *reinterpret_cast<const bf16x8*>(&WL[lg * 256 + (16 + l15) * 8]);
        #pragma unroll
        for (int q = 0; q < 2; ++q) {
            u32x4 w;
            #pragma unroll
            for (int i = 0; i < 4; ++i)
                w[i] = pack_trunc(tmp2[q][i][0], tmp2[q][i][1]);   // exact (values are bf16)
            const bf16x8 af = __builtin_bit_cast(bf16x8, w);
            acc[q][0] = __builtin_amdgcn_mfma_f32_16x16x32_bf16(af, bb0, acc[q][0], 0, 0, 0);
            acc[q][1] = __builtin_amdgcn_mfma_f32_16x16x32_bf16(af, bb1, acc[q][1], 0, 0, 0);
        }
    }

    // ---- epilogue: 4x4 quad transpose, then lane-local basis2 contraction ----
    // C layout (verified): lane holds col a = l15 + 16t (k2 = lane&3), rows
    // edge = q*16 + lg*4 + r in regs. Quad transpose (lane-pos p <-> reg idx):
    // after it, lane p holds all four k2 values of edge q*16 + lg*4 + p.
    const int m2l = (lane >> 2) & 3;
    const int p0  = lane & 1;
    const int p1  = (lane >> 1) & 1;
    #pragma unroll
    for (int q = 0; q < 2; ++q) {
        const int egp = base + wid * 32 + q * 16 + lg * 4 + (lane & 3);
        const f32x4* bp = reinterpret_cast<const f32x4*>(basis2 + egp * 16);
        f32x4 bsr0 = bp[0], bsr1 = bp[1], bsr2 = bp[2], bsr3 = bp[3];
        #pragma unroll
        for (int t = 0; t < 2; ++t) {
            float v0 = acc[q][t][0], v1 = acc[q][t][1];
            float v2 = acc[q][t][2], v3 = acc[q][t][3];
            // step 1 (xor 1): even.v1 <-> odd.v0, even.v3 <-> odd.v2
            float s0 = p0 ? v0 : v1;
            float r0 = __shfl_xor(s0, 1);
            if (p0) v0 = r0; else v1 = r0;
            float s1 = p0 ? v2 : v3;
            float r1 = __shfl_xor(s1, 1);
            if (p0) v2 = r1; else v3 = r1;
            // step 2 (xor 2): low.v2 <-> high.v0, low.v3 <-> high.v1
            float u0 = p1 ? v0 : v2;
            float w0 = __shfl_xor(u0, 2);
            if (p1) v0 = w0; else v2 = w0;
            float u1 = p1 ? v1 : v3;
            float w1 = __shfl_xor(u1, 2);
            if (p1) v1 = w1; else v3 = w1;
            // v[s] = C[edge egp][m2 = t*4+m2l, k2 = s] -> lane-local contraction
            f32x4 o = v0 * bsr0;
            o += v1 * bsr1;
            o += v2 * bsr2;
            o += v3 * bsr3;
            *reinterpret_cast<f32x4*>(out + egp * 32 + (t * 4 + m2l) * 4) = o;
        }
    }
}

extern "C" void kernel_launch(void* const* d_in, const int* in_sizes, int n_in,
                              void* d_out, int out_size, void* d_ws, size_t ws_size,
                              hipStream_t stream) {
    const float* basis1 = (const float*)d_in[0];
    const float* basis2 = (const float*)d_in[1];
    const float* ef     = (const float*)d_in[2];
    const float* f      = (const float*)d_in[3];
    const int*   src    = (const int*)  d_in[4];
    const float* w1     = (const float*)d_in[5];
    const float* b1     = (const float*)d_in[6];
    const float* w2     = (const float*)d_in[7];
    const float* b2     = (const float*)d_in[8];
    float* out = (float*)d_out;

    const int E = in_sizes[4];            // 262144
    const int nblocks = E / BM;           // 1024

    equiv_conv_mfma<<<nblocks, TPB, 0, stream>>>(
        basis1, basis2, ef, f, src, w1, b1, w2, b2, out);
}